// Round 5
// baseline (229.193 us; speedup 1.0000x reference)
//
#include <hip/hip_runtime.h>

// Problem constants: b=1, n=4 views, f=8 frames, l=256, C=320, H=8, d=40
#define MROWS 8192   // (b*f) * (n*l)
#define CDIM  320
#define QPAD  512    // padded row stride for Q/K/Qi: 8 heads x 64 (cols 40..63 zero)

typedef __attribute__((ext_vector_type(8))) short bf16x8;
typedef __attribute__((ext_vector_type(4))) float f32x4;

__device__ __forceinline__ unsigned bfbits(float x) {  // round-half-up bf16 bits (hi16)
  union { float f; unsigned u; } a; a.f = x;
  return a.u + 0x8000u;
}
__device__ __forceinline__ unsigned pack2bf(float a, float b) {
  return (bfbits(a) >> 16) | (bfbits(b) & 0xffff0000u);
}
__device__ __forceinline__ void splitbf(float x, short& hi, short& lo) {
  unsigned hu = bfbits(x) & 0xffff0000u;
  union { unsigned u; float f; } h; h.u = hu;
  hi = (short)(hu >> 16);
  lo = (short)(bfbits(x - h.f) >> 16);
}

// rearrange '(b n f) l c -> (b f) (n l) c' row map (involution)
__device__ __forceinline__ int swizzle_row(int r) {
  int ff = r >> 10;
  int t  = r & 1023;
  int nn = t >> 8;
  int ll = t & 255;
  return nn * 2048 + ff * 256 + ll;
}

// ---------------------------------------------------------------------------
// P1: Wc = Wo_i2v @ Wo, fp32, 64x64 tiles, grid (5,5). Tiny (65 MFLOP).
// ---------------------------------------------------------------------------
__global__ __launch_bounds__(256) void wc_kernel(
    const float* __restrict__ Woi, const float* __restrict__ Wo,
    float* __restrict__ Wc)
{
  const int r0 = blockIdx.x * 64, c0 = blockIdx.y * 64;
  __shared__ float As[64][36];
  __shared__ float Bs[32][68];
  const int tid = threadIdx.x, tx = tid & 15, ty = tid >> 4;
  float acc[4][4] = {};

  const int ra = tid >> 3, kq = (tid & 7) * 4;
  const int kb = tid >> 4, cq = (tid & 15) * 4;

  for (int k0 = 0; k0 < 320; k0 += 32) {
    float4 a1 = *(const float4*)(Woi + (size_t)(r0 + ra) * 320 + k0 + kq);
    float4 a2 = *(const float4*)(Woi + (size_t)(r0 + ra + 32) * 320 + k0 + kq);
    float4 b1 = *(const float4*)(Wo + (size_t)(k0 + kb) * 320 + c0 + cq);
    float4 b2 = *(const float4*)(Wo + (size_t)(k0 + kb + 16) * 320 + c0 + cq);
    __syncthreads();
    *(float4*)&As[ra][kq] = a1;
    *(float4*)&As[ra + 32][kq] = a2;
    *(float4*)&Bs[kb][cq] = b1;
    *(float4*)&Bs[kb + 16][cq] = b2;
    __syncthreads();
    #pragma unroll
    for (int kk = 0; kk < 32; ++kk) {
      float4 bv = *(const float4*)&Bs[kk][tx * 4];
      #pragma unroll
      for (int i = 0; i < 4; ++i) {
        float a = As[ty * 4 + i][kk];
        acc[i][0] = fmaf(a, bv.x, acc[i][0]);
        acc[i][1] = fmaf(a, bv.y, acc[i][1]);
        acc[i][2] = fmaf(a, bv.z, acc[i][2]);
        acc[i][3] = fmaf(a, bv.w, acc[i][3]);
      }
    }
  }
  #pragma unroll
  for (int i = 0; i < 4; ++i) {
    float4 v = make_float4(acc[i][0], acc[i][1], acc[i][2], acc[i][3]);
    *(float4*)(Wc + (size_t)(r0 + ty * 4 + i) * 320 + c0 + tx * 4) = v;
  }
}

// ---------------------------------------------------------------------------
// P2: pack/split/zero everything.
//  [0,64):    hidden gather+split -> Ah/Al [8192][320] (swizzled rows)
//  [64,128):  proj weights -> WTh/WTl[wi][n][k] (transposed; Q-weights scaled)
//  [128,160): WF = [Wo; Wc] -> WFh/WFl[n][640] (transposed)
//  [160,168): bc[n] = bo[n] + sum_j boi[j]*Wo[j][n]
//  [168,264): zero pad cols 40..63 of each head slice in Qp/Kp/Qip
// ---------------------------------------------------------------------------
__global__ __launch_bounds__(256) void pack_kernel(
    const float* __restrict__ hidden,
    const float* __restrict__ Wq, const float* __restrict__ Wk,
    const float* __restrict__ Wv, const float* __restrict__ Wqi,
    const float* __restrict__ Wo, const float* __restrict__ Wc,
    const float* __restrict__ bo, const float* __restrict__ boi,
    short* __restrict__ Ah, short* __restrict__ Al,
    short* __restrict__ WTh, short* __restrict__ WTl,
    short* __restrict__ WFh, short* __restrict__ WFl,
    float* __restrict__ bc,
    short* __restrict__ Qp, short* __restrict__ Kp, short* __restrict__ Qip,
    float qscale)
{
  const int b = blockIdx.x, tid = threadIdx.x;
  if (b < 64) {
    const int r0 = b * 128;
    for (int e = tid; e < 128 * 80; e += 256) {
      int r = e / 80, cq = (e % 80) * 4;
      float4 x = *(const float4*)(hidden + (size_t)swizzle_row(r0 + r) * 320 + cq);
      union { ushort4 v; short s[4]; } h, l;
      splitbf(x.x, h.s[0], l.s[0]); splitbf(x.y, h.s[1], l.s[1]);
      splitbf(x.z, h.s[2], l.s[2]); splitbf(x.w, h.s[3], l.s[3]);
      *(ushort4*)&Ah[(size_t)(r0 + r) * 320 + cq] = h.v;
      *(ushort4*)&Al[(size_t)(r0 + r) * 320 + cq] = l.v;
    }
  } else if (b < 128) {
    const int t2 = b - 64, wi = t2 >> 4, seg = t2 & 15;
    const float* W = wi == 0 ? Wq : wi == 1 ? Wk : wi == 2 ? Wv : Wqi;
    const float s = (wi == 0 || wi == 3) ? qscale : 1.0f;
    short* th = WTh + (size_t)wi * 320 * 320;
    short* tl = WTl + (size_t)wi * 320 * 320;
    for (int e = tid; e < 20 * 320; e += 256) {
      int n = seg * 20 + e / 320, k = e % 320;
      short hi, lo;
      splitbf(W[(size_t)k * 320 + n] * s, hi, lo);
      th[(size_t)n * 320 + k] = hi;
      tl[(size_t)n * 320 + k] = lo;
    }
  } else if (b < 160) {
    const int t2 = b - 128;
    for (int e = tid; e < 10 * 640; e += 256) {
      int n = t2 * 10 + e / 640, k = e % 640;
      float x = (k < 320) ? Wo[(size_t)k * 320 + n] : Wc[(size_t)(k - 320) * 320 + n];
      short hi, lo;
      splitbf(x, hi, lo);
      WFh[(size_t)n * 640 + k] = hi;
      WFl[(size_t)n * 640 + k] = lo;
    }
  } else if (b < 168) {
    const int n = (b - 160) * 40 + tid;
    if (tid < 40) {
      float s = bo[n];
      for (int j = 0; j < 320; ++j) s = fmaf(boi[j], Wo[(size_t)j * 320 + n], s);
      bc[n] = s;
    }
  } else {
    const int bz = b - 168, buf = bz >> 5, seg = bz & 31;
    short* P = buf == 0 ? Qp : buf == 1 ? Kp : Qip;
    const uint4 z = make_uint4(0, 0, 0, 0);
    for (int e = tid; e < 256 * 24; e += 256) {
      int row = (seg << 8) + (e / 24);
      int cc = e % 24, h = cc / 3, c3 = cc % 3;
      *(uint4*)&P[(size_t)row * QPAD + h * 64 + 40 + c3 * 8] = z;
    }
  }
}

// ---------------------------------------------------------------------------
// Split-bf16 MFMA GEMM. Tile 128x64, BK=32, 256 thr = 4 waves.
// Al != null -> 3-term (AhBh+AhBl+AlBh); Al == null -> 2-term (AhBh+AhBl).
// mode 0 (proj, grid.y=20): bf16 out into PADDED [8192][512] (Q/K/Qi) or
//   transposed V^T[c][8192] (wi==2). mode 1 (final, grid.y=5): K=640,
//   fp32 out + bias + row scatter.
// ---------------------------------------------------------------------------
__global__ __launch_bounds__(256, 3) void mfma_gemm(
    const short* __restrict__ Ah, const short* __restrict__ Al,
    const short* __restrict__ BTh, const short* __restrict__ BTl,
    int K, int mode,
    short* __restrict__ Qp, short* __restrict__ Kp,
    short* __restrict__ Vt, short* __restrict__ Qip,
    float* __restrict__ Of, const float* __restrict__ bias)
{
  const int tid  = threadIdx.x;
  const int wave = tid >> 6;
  const int lane = tid & 63;
  const int quad = lane >> 4;
  const int l16  = lane & 15;
  const int row0 = blockIdx.x * 128;

  const short *bth, *btl;
  int nbase, wi = 0;
  if (mode == 0) {
    const int ct = blockIdx.y;
    wi = ct / 5;
    bth = BTh + (size_t)wi * 320 * 320;
    btl = BTl + (size_t)wi * 320 * 320;
    nbase = (ct % 5) * 64;
  } else {
    bth = BTh; btl = BTl;
    nbase = blockIdx.y * 64;
  }

  __shared__ short Ash[128][40], Asl[128][40];
  __shared__ short Bsh[64][40],  Bsl[64][40];

  f32x4 acc[2][4];
  #pragma unroll
  for (int mt = 0; mt < 2; ++mt)
    #pragma unroll
    for (int nt = 0; nt < 4; ++nt) acc[mt][nt] = (f32x4){0.f, 0.f, 0.f, 0.f};

  const int ar = tid >> 2, akc = (tid & 3) * 8;
  const int bn = tid >> 2, bkc = (tid & 3) * 8;

  const short* pa_h = Ah + (size_t)(row0 + ar) * K + akc;
  const short* pa_l = Al ? Al + (size_t)(row0 + ar) * K + akc : nullptr;
  const short* pb_h = bth + (size_t)(nbase + bn) * K + bkc;
  const short* pb_l = btl + (size_t)(nbase + bn) * K + bkc;

  for (int k0 = 0; k0 < K; k0 += 32) {
    uint4 ah1 = *(const uint4*)(pa_h + k0);
    uint4 ah2 = *(const uint4*)(pa_h + (size_t)64 * K + k0);
    uint4 al1, al2;
    if (Al) {
      al1 = *(const uint4*)(pa_l + k0);
      al2 = *(const uint4*)(pa_l + (size_t)64 * K + k0);
    }
    uint4 bh = *(const uint4*)(pb_h + k0);
    uint4 bl = *(const uint4*)(pb_l + k0);
    __syncthreads();
    *(uint4*)&Ash[ar][akc]      = ah1;
    *(uint4*)&Ash[ar + 64][akc] = ah2;
    if (Al) {
      *(uint4*)&Asl[ar][akc]      = al1;
      *(uint4*)&Asl[ar + 64][akc] = al2;
    }
    *(uint4*)&Bsh[bn][bkc] = bh;
    *(uint4*)&Bsl[bn][bkc] = bl;
    __syncthreads();

    bf16x8 afh[2], afl[2], bfh[4], bfl[4];
    #pragma unroll
    for (int mt = 0; mt < 2; ++mt) {
      afh[mt] = *(const bf16x8*)&Ash[wave * 32 + mt * 16 + l16][quad * 8];
      if (Al) afl[mt] = *(const bf16x8*)&Asl[wave * 32 + mt * 16 + l16][quad * 8];
    }
    #pragma unroll
    for (int nt = 0; nt < 4; ++nt) {
      bfh[nt] = *(const bf16x8*)&Bsh[nt * 16 + l16][quad * 8];
      bfl[nt] = *(const bf16x8*)&Bsl[nt * 16 + l16][quad * 8];
    }
    #pragma unroll
    for (int mt = 0; mt < 2; ++mt)
      #pragma unroll
      for (int nt = 0; nt < 4; ++nt) {
        acc[mt][nt] = __builtin_amdgcn_mfma_f32_16x16x32_bf16(afh[mt], bfh[nt], acc[mt][nt], 0, 0, 0);
        acc[mt][nt] = __builtin_amdgcn_mfma_f32_16x16x32_bf16(afh[mt], bfl[nt], acc[mt][nt], 0, 0, 0);
        if (Al)
          acc[mt][nt] = __builtin_amdgcn_mfma_f32_16x16x32_bf16(afl[mt], bfh[nt], acc[mt][nt], 0, 0, 0);
      }
  }

  // epilogue: C row = quad*4+r (m), col = l16 (n)
  if (mode == 0) {
    if (wi == 2) {
      #pragma unroll
      for (int mt = 0; mt < 2; ++mt)
        #pragma unroll
        for (int nt = 0; nt < 4; ++nt) {
          const int col  = nbase + nt * 16 + l16;
          const int rowb = row0 + wave * 32 + mt * 16 + quad * 4;
          union { ushort4 v; short s[4]; } pk;
          #pragma unroll
          for (int r = 0; r < 4; ++r) pk.s[r] = (short)(bfbits(acc[mt][nt][r]) >> 16);
          *(ushort4*)&Vt[(size_t)col * MROWS + rowb] = pk.v;
        }
    } else {
      short* Op = wi == 0 ? Qp : wi == 1 ? Kp : Qip;
      #pragma unroll
      for (int mt = 0; mt < 2; ++mt)
        #pragma unroll
        for (int nt = 0; nt < 4; ++nt) {
          const int col  = nbase + nt * 16 + l16;
          const int h    = col / 40;
          const int pcol = h * 64 + (col - h * 40);
          const int rowb = row0 + wave * 32 + mt * 16 + quad * 4;
          #pragma unroll
          for (int r = 0; r < 4; ++r)
            Op[(size_t)(rowb + r) * QPAD + pcol] = (short)(bfbits(acc[mt][nt][r]) >> 16);
        }
    }
  } else {
    #pragma unroll
    for (int mt = 0; mt < 2; ++mt)
      #pragma unroll
      for (int nt = 0; nt < 4; ++nt) {
        const int col  = nbase + nt * 16 + l16;
        const int rowb = row0 + wave * 32 + mt * 16 + quad * 4;
        const float bb = bias[col];
        #pragma unroll
        for (int r = 0; r < 4; ++r)
          Of[(size_t)swizzle_row(rowb + r) * CDIM + col] = acc[mt][nt][r] + bb;
      }
  }
}

// ---------------------------------------------------------------------------
// Flash attention, bf16 MFMA, static-max softmax. ONE WAVE per block, no
// barriers, no K/V LDS staging: K and V^T fragments load straight from
// global (L2-resident padded layouts). LDS holds only the wave-private
// P-transpose buffer. Wave owns 64 q-rows (qt=4); KV step = 64 keys.
// grid = (16 qblk, 8 heads, 16 = bf + 8*variant).
// ---------------------------------------------------------------------------
__global__ __launch_bounds__(64, 2) void attn_kernel(
    const short* __restrict__ Qp, const short* __restrict__ Qip,
    const short* __restrict__ Kp, const short* __restrict__ Vtg,
    short* __restrict__ AOh)
{
  const int qblk = blockIdx.x;   // 0..15
  const int hh   = blockIdx.y;   // 0..7
  const int zz   = blockIdx.z;   // 0..15
  const int var  = zz >> 3;
  const int bf   = zz & 7;
  const int lane = threadIdx.x;
  const int quad = lane >> 4;
  const int l16  = lane & 15;

  const short* Q = var ? Qip : Qp;
  const int kvbase = var ? 0 : (bf << 10);
  const int coff = var * 320 + hh * 40;

  __shared__ short Ps[4][16][72];   // [qt][qrow][64 keys + pad]

  // Q fragments (A/B-operand layout; kd 32..63 slice has zeros in 40..63)
  bf16x8 qf0[4], qf1[4];
  #pragma unroll
  for (int qt = 0; qt < 4; ++qt) {
    const short* qp = Q + (size_t)((bf << 10) + (qblk << 6) + (qt << 4) + l16) * QPAD + hh * 64;
    qf0[qt] = *(const bf16x8*)(qp + quad * 8);
    qf1[qt] = *(const bf16x8*)(qp + 32 + quad * 8);
  }

  f32x4 acc[4][3];
  float lsum[4];
  #pragma unroll
  for (int qt = 0; qt < 4; ++qt) {
    lsum[qt] = 0.f;
    #pragma unroll
    for (int t = 0; t < 3; ++t) acc[qt][t] = (f32x4){0.f, 0.f, 0.f, 0.f};
  }

  const short* Kb = Kp + (size_t)kvbase * QPAD + hh * 64;
  const short* Vb = Vtg + (size_t)(hh * 40) * MROWS + kvbase;

  for (int s0 = 0; s0 < 1024; s0 += 64) {
    // ---- K fragments direct from global (L2) ----
    bf16x8 kb0[4], kb1[4];
    #pragma unroll
    for (int kt = 0; kt < 4; ++kt) {
      const short* kp = Kb + (size_t)(s0 + kt * 16 + l16) * QPAD;
      kb0[kt] = *(const bf16x8*)(kp + quad * 8);
      kb1[kt] = *(const bf16x8*)(kp + 32 + quad * 8);
    }

    // ---- S^T = K @ Q^T, exp, pack, P -> LDS (b64 stores, conflict-free) ----
    #pragma unroll
    for (int qt = 0; qt < 4; ++qt) {
      float ls = 0.f;
      #pragma unroll
      for (int kt = 0; kt < 4; ++kt) {
        f32x4 st = (f32x4){0.f, 0.f, 0.f, 0.f};
        st = __builtin_amdgcn_mfma_f32_16x16x32_bf16(kb0[kt], qf0[qt], st, 0, 0, 0);
        st = __builtin_amdgcn_mfma_f32_16x16x32_bf16(kb1[kt], qf1[qt], st, 0, 0, 0);
        float p0 = __expf(st[0]);
        float p1 = __expf(st[1]);
        float p2 = __expf(st[2]);
        float p3 = __expf(st[3]);
        ls += (p0 + p1) + (p2 + p3);
        uint2 pk;
        pk.x = pack2bf(p0, p1);
        pk.y = pack2bf(p2, p3);
        *(uint2*)&Ps[qt][l16][kt * 16 + quad * 4] = pk;
      }
      lsum[qt] += ls;
    }

    // wave-internal LDS RAW (cross-lane): drain before reading P fragments
    asm volatile("s_waitcnt lgkmcnt(0)" ::: "memory");

    // ---- V^T fragments direct from global (L2) ----
    bf16x8 vf[2][3];
    #pragma unroll
    for (int kh = 0; kh < 2; ++kh)
      #pragma unroll
      for (int t = 0; t < 3; ++t)
        vf[kh][t] = *(const bf16x8*)(Vb + (size_t)(t * 16 + l16) * MROWS + s0 + kh * 32 + quad * 8);

    // ---- P @ V ----
    #pragma unroll
    for (int qt = 0; qt < 4; ++qt) {
      bf16x8 pa0 = *(const bf16x8*)&Ps[qt][l16][quad * 8];
      bf16x8 pa1 = *(const bf16x8*)&Ps[qt][l16][32 + quad * 8];
      #pragma unroll
      for (int t = 0; t < 3; ++t) {
        acc[qt][t] = __builtin_amdgcn_mfma_f32_16x16x32_bf16(pa0, vf[0][t], acc[qt][t], 0, 0, 0);
        acc[qt][t] = __builtin_amdgcn_mfma_f32_16x16x32_bf16(pa1, vf[1][t], acc[qt][t], 0, 0, 0);
      }
    }
  }

  // ---- epilogue: normalize by deferred denominator, write bf16 (hi only) ----
  #pragma unroll
  for (int qt = 0; qt < 4; ++qt) {
    float li = lsum[qt];
    li += __shfl_xor(li, 16);
    li += __shfl_xor(li, 32);
    float inv = 1.f / li;
    float invr[4];
    #pragma unroll
    for (int r = 0; r < 4; ++r) invr[r] = __shfl(inv, quad * 4 + r, 64);

    const int baserow = (bf << 10) + (qblk << 6) + (qt << 4) + quad * 4;
    #pragma unroll
    for (int t = 0; t < 3; ++t) {
      int dcol = t * 16 + l16;
      if (dcol < 40) {
        short* op = AOh + (size_t)baserow * 640 + coff + dcol;
        #pragma unroll
        for (int r = 0; r < 4; ++r)
          op[(size_t)r * 640] = (short)(bfbits(acc[qt][t][r] * invr[r]) >> 16);
      }
    }
  }
}

// ---------------------------------------------------------------------------
extern "C" void kernel_launch(void* const* d_in, const int* in_sizes, int n_in,
                              void* d_out, int out_size, void* d_ws, size_t ws_size,
                              hipStream_t stream) {
  const float* hidden  = (const float*)d_in[0];
  const float* Wq      = (const float*)d_in[1];
  const float* Wk      = (const float*)d_in[2];
  const float* Wv      = (const float*)d_in[3];
  const float* Wo      = (const float*)d_in[4];
  const float* bo      = (const float*)d_in[5];
  const float* Wq_i2v  = (const float*)d_in[6];
  const float* Wo_i2v  = (const float*)d_in[7];
  const float* bo_i2v  = (const float*)d_in[8];
  float* out = (float*)d_out;

  const size_t SZ  = (size_t)MROWS * CDIM;    // 2,621,440
  const size_t SZP = (size_t)MROWS * QPAD;    // 4,194,304
  short* Ah  = (short*)d_ws;                  // [8192][320] split hidden (hi)
  short* Al  = Ah + SZ;                       // [8192][320] (lo)
  short* AOh = Ah;                            // attn out [8192][640] — aliases Ah/Al (dead after G1)
  short* Qp  = Al + SZ;                       // [8192][512] padded
  short* Kp  = Qp + SZP;                      // [8192][512] padded
  short* Qip = Kp + SZP;                      // [8192][512] padded
  short* Vt  = Qip + SZP;                     // [328][8192] (rows 320..327 slack)
  short* WTh = Vt + (size_t)328 * MROWS;
  short* WTl = WTh + 409600;
  short* WFh = WTl + 409600;                  // [320][640] transposed [Wo; Wc]
  short* WFl = WFh + 204800;
  float* Wc  = (float*)(WFl + 204800);
  float* bc  = Wc + 102400;

  const float qscale = 0.15811388300841898f;  // 1/sqrt(40), folded into Q/Q_i2v

  // P1: Wc = Wo_i2v @ Wo
  wc_kernel<<<dim3(5, 5), 256, 0, stream>>>(Wo_i2v, Wo, Wc);

  // P2: split/transpose/zero-pad
  pack_kernel<<<dim3(264), 256, 0, stream>>>(
      hidden, Wq, Wk, Wv, Wq_i2v, Wo, Wc, bo, bo_i2v,
      Ah, Al, WTh, WTl, WFh, WFl, bc, Qp, Kp, Qip, qscale);

  // G1: projections (3-term split MFMA) -> padded Q/K/Qi + V^T
  mfma_gemm<<<dim3(64, 20), 256, 0, stream>>>(
      Ah, Al, WTh, WTl, 320, 0, Qp, Kp, Vt, Qip, nullptr, nullptr);

  // A: both attentions (base: per-frame KV; i2v: frame-0 KV) -> AOh [8192][640]
  attn_kernel<<<dim3(16, 8, 16), 64, 0, stream>>>(Qp, Qip, Kp, Vt, AOh);

  // G2: out = [base|i2v] @ [Wo; Wo_i2v@Wo] + (bo + bo_i2v@Wo), scattered (2-term)
  mfma_gemm<<<dim3(64, 5), 256, 0, stream>>>(
      AOh, nullptr, WFh, WFl, 640, 1, nullptr, nullptr, nullptr, nullptr, out, bc);
}

// Round 6
// 219.813 us; speedup vs baseline: 1.0427x; 1.0427x over previous
//
#include <hip/hip_runtime.h>

// Problem constants: b=1, n=4 views, f=8 frames, l=256, C=320, H=8, d=40
#define MROWS 8192   // (b*f) * (n*l)
#define CDIM  320
#define QPAD  512    // padded row stride for Q/K/Qi: 8 heads x 64 (cols 40..63 zero)

typedef __attribute__((ext_vector_type(8))) short bf16x8;
typedef __attribute__((ext_vector_type(4))) float f32x4;

__device__ __forceinline__ unsigned bfbits(float x) {  // round-half-up bf16 bits (hi16)
  union { float f; unsigned u; } a; a.f = x;
  return a.u + 0x8000u;
}
__device__ __forceinline__ unsigned pack2bf(float a, float b) {
  return (bfbits(a) >> 16) | (bfbits(b) & 0xffff0000u);
}
__device__ __forceinline__ void splitbf(float x, short& hi, short& lo) {
  unsigned hu = bfbits(x) & 0xffff0000u;
  union { unsigned u; float f; } h; h.u = hu;
  hi = (short)(hu >> 16);
  lo = (short)(bfbits(x - h.f) >> 16);
}

// rearrange '(b n f) l c -> (b f) (n l) c' row map (involution)
__device__ __forceinline__ int swizzle_row(int r) {
  int ff = r >> 10;
  int t  = r & 1023;
  int nn = t >> 8;
  int ll = t & 255;
  return nn * 2048 + ff * 256 + ll;
}

// ---------------------------------------------------------------------------
// P1: Wc = Wo_i2v @ Wo, fp32, 64x64 tiles, grid (5,5). Tiny (65 MFLOP).
// ---------------------------------------------------------------------------
__global__ __launch_bounds__(256) void wc_kernel(
    const float* __restrict__ Woi, const float* __restrict__ Wo,
    float* __restrict__ Wc)
{
  const int r0 = blockIdx.x * 64, c0 = blockIdx.y * 64;
  __shared__ float As[64][36];
  __shared__ float Bs[32][68];
  const int tid = threadIdx.x, tx = tid & 15, ty = tid >> 4;
  float acc[4][4] = {};

  const int ra = tid >> 3, kq = (tid & 7) * 4;
  const int kb = tid >> 4, cq = (tid & 15) * 4;

  for (int k0 = 0; k0 < 320; k0 += 32) {
    float4 a1 = *(const float4*)(Woi + (size_t)(r0 + ra) * 320 + k0 + kq);
    float4 a2 = *(const float4*)(Woi + (size_t)(r0 + ra + 32) * 320 + k0 + kq);
    float4 b1 = *(const float4*)(Wo + (size_t)(k0 + kb) * 320 + c0 + cq);
    float4 b2 = *(const float4*)(Wo + (size_t)(k0 + kb + 16) * 320 + c0 + cq);
    __syncthreads();
    *(float4*)&As[ra][kq] = a1;
    *(float4*)&As[ra + 32][kq] = a2;
    *(float4*)&Bs[kb][cq] = b1;
    *(float4*)&Bs[kb + 16][cq] = b2;
    __syncthreads();
    #pragma unroll
    for (int kk = 0; kk < 32; ++kk) {
      float4 bv = *(const float4*)&Bs[kk][tx * 4];
      #pragma unroll
      for (int i = 0; i < 4; ++i) {
        float a = As[ty * 4 + i][kk];
        acc[i][0] = fmaf(a, bv.x, acc[i][0]);
        acc[i][1] = fmaf(a, bv.y, acc[i][1]);
        acc[i][2] = fmaf(a, bv.z, acc[i][2]);
        acc[i][3] = fmaf(a, bv.w, acc[i][3]);
      }
    }
  }
  #pragma unroll
  for (int i = 0; i < 4; ++i) {
    float4 v = make_float4(acc[i][0], acc[i][1], acc[i][2], acc[i][3]);
    *(float4*)(Wc + (size_t)(r0 + ty * 4 + i) * 320 + c0 + tx * 4) = v;
  }
}

// ---------------------------------------------------------------------------
// P2: pack/split/zero everything.
//  [0,64):    hidden gather+split -> Ah/Al [8192][320] (swizzled rows)
//  [64,128):  proj weights -> WTh/WTl[wi][n][k] (transposed; Q-weights scaled)
//  [128,160): WF = [Wo; Wc] -> WFh/WFl[n][640] (transposed)
//  [160,168): bc[n] = bo[n] + sum_j boi[j]*Wo[j][n]
//  [168,264): zero pad cols 40..63 of each head slice in Qp/Kp/Qip
// ---------------------------------------------------------------------------
__global__ __launch_bounds__(256) void pack_kernel(
    const float* __restrict__ hidden,
    const float* __restrict__ Wq, const float* __restrict__ Wk,
    const float* __restrict__ Wv, const float* __restrict__ Wqi,
    const float* __restrict__ Wo, const float* __restrict__ Wc,
    const float* __restrict__ bo, const float* __restrict__ boi,
    short* __restrict__ Ah, short* __restrict__ Al,
    short* __restrict__ WTh, short* __restrict__ WTl,
    short* __restrict__ WFh, short* __restrict__ WFl,
    float* __restrict__ bc,
    short* __restrict__ Qp, short* __restrict__ Kp, short* __restrict__ Qip,
    float qscale)
{
  const int b = blockIdx.x, tid = threadIdx.x;
  if (b < 64) {
    const int r0 = b * 128;
    for (int e = tid; e < 128 * 80; e += 256) {
      int r = e / 80, cq = (e % 80) * 4;
      float4 x = *(const float4*)(hidden + (size_t)swizzle_row(r0 + r) * 320 + cq);
      union { ushort4 v; short s[4]; } h, l;
      splitbf(x.x, h.s[0], l.s[0]); splitbf(x.y, h.s[1], l.s[1]);
      splitbf(x.z, h.s[2], l.s[2]); splitbf(x.w, h.s[3], l.s[3]);
      *(ushort4*)&Ah[(size_t)(r0 + r) * 320 + cq] = h.v;
      *(ushort4*)&Al[(size_t)(r0 + r) * 320 + cq] = l.v;
    }
  } else if (b < 128) {
    const int t2 = b - 64, wi = t2 >> 4, seg = t2 & 15;
    const float* W = wi == 0 ? Wq : wi == 1 ? Wk : wi == 2 ? Wv : Wqi;
    const float s = (wi == 0 || wi == 3) ? qscale : 1.0f;
    short* th = WTh + (size_t)wi * 320 * 320;
    short* tl = WTl + (size_t)wi * 320 * 320;
    for (int e = tid; e < 20 * 320; e += 256) {
      int n = seg * 20 + e / 320, k = e % 320;
      short hi, lo;
      splitbf(W[(size_t)k * 320 + n] * s, hi, lo);
      th[(size_t)n * 320 + k] = hi;
      tl[(size_t)n * 320 + k] = lo;
    }
  } else if (b < 160) {
    const int t2 = b - 128;
    for (int e = tid; e < 10 * 640; e += 256) {
      int n = t2 * 10 + e / 640, k = e % 640;
      float x = (k < 320) ? Wo[(size_t)k * 320 + n] : Wc[(size_t)(k - 320) * 320 + n];
      short hi, lo;
      splitbf(x, hi, lo);
      WFh[(size_t)n * 640 + k] = hi;
      WFl[(size_t)n * 640 + k] = lo;
    }
  } else if (b < 168) {
    const int n = (b - 160) * 40 + tid;
    if (tid < 40) {
      float s = bo[n];
      for (int j = 0; j < 320; ++j) s = fmaf(boi[j], Wo[(size_t)j * 320 + n], s);
      bc[n] = s;
    }
  } else {
    const int bz = b - 168, buf = bz >> 5, seg = bz & 31;
    short* P = buf == 0 ? Qp : buf == 1 ? Kp : Qip;
    const uint4 z = make_uint4(0, 0, 0, 0);
    for (int e = tid; e < 256 * 24; e += 256) {
      int row = (seg << 8) + (e / 24);
      int cc = e % 24, h = cc / 3, c3 = cc % 3;
      *(uint4*)&P[(size_t)row * QPAD + h * 64 + 40 + c3 * 8] = z;
    }
  }
}

// ---------------------------------------------------------------------------
// Split-bf16 MFMA GEMM. Tile 128x64, BK=32, 256 thr = 4 waves.
// Al != null -> 3-term (AhBh+AhBl+AlBh); Al == null -> 2-term (AhBh+AhBl).
// mode 0 (proj, grid.y=20): bf16 out into PADDED [8192][512] (Q/K/Qi) or
//   transposed V^T[c][8192] (wi==2). mode 1 (final, grid.y=5): K=640,
//   fp32 out + bias + row scatter.
// ---------------------------------------------------------------------------
__global__ __launch_bounds__(256, 3) void mfma_gemm(
    const short* __restrict__ Ah, const short* __restrict__ Al,
    const short* __restrict__ BTh, const short* __restrict__ BTl,
    int K, int mode,
    short* __restrict__ Qp, short* __restrict__ Kp,
    short* __restrict__ Vt, short* __restrict__ Qip,
    float* __restrict__ Of, const float* __restrict__ bias)
{
  const int tid  = threadIdx.x;
  const int wave = tid >> 6;
  const int lane = tid & 63;
  const int quad = lane >> 4;
  const int l16  = lane & 15;
  const int row0 = blockIdx.x * 128;

  const short *bth, *btl;
  int nbase, wi = 0;
  if (mode == 0) {
    const int ct = blockIdx.y;
    wi = ct / 5;
    bth = BTh + (size_t)wi * 320 * 320;
    btl = BTl + (size_t)wi * 320 * 320;
    nbase = (ct % 5) * 64;
  } else {
    bth = BTh; btl = BTl;
    nbase = blockIdx.y * 64;
  }

  __shared__ short Ash[128][40], Asl[128][40];
  __shared__ short Bsh[64][40],  Bsl[64][40];

  f32x4 acc[2][4];
  #pragma unroll
  for (int mt = 0; mt < 2; ++mt)
    #pragma unroll
    for (int nt = 0; nt < 4; ++nt) acc[mt][nt] = (f32x4){0.f, 0.f, 0.f, 0.f};

  const int ar = tid >> 2, akc = (tid & 3) * 8;
  const int bn = tid >> 2, bkc = (tid & 3) * 8;

  const short* pa_h = Ah + (size_t)(row0 + ar) * K + akc;
  const short* pa_l = Al ? Al + (size_t)(row0 + ar) * K + akc : nullptr;
  const short* pb_h = bth + (size_t)(nbase + bn) * K + bkc;
  const short* pb_l = btl + (size_t)(nbase + bn) * K + bkc;

  for (int k0 = 0; k0 < K; k0 += 32) {
    uint4 ah1 = *(const uint4*)(pa_h + k0);
    uint4 ah2 = *(const uint4*)(pa_h + (size_t)64 * K + k0);
    uint4 al1, al2;
    if (Al) {
      al1 = *(const uint4*)(pa_l + k0);
      al2 = *(const uint4*)(pa_l + (size_t)64 * K + k0);
    }
    uint4 bh = *(const uint4*)(pb_h + k0);
    uint4 bl = *(const uint4*)(pb_l + k0);
    __syncthreads();
    *(uint4*)&Ash[ar][akc]      = ah1;
    *(uint4*)&Ash[ar + 64][akc] = ah2;
    if (Al) {
      *(uint4*)&Asl[ar][akc]      = al1;
      *(uint4*)&Asl[ar + 64][akc] = al2;
    }
    *(uint4*)&Bsh[bn][bkc] = bh;
    *(uint4*)&Bsl[bn][bkc] = bl;
    __syncthreads();

    bf16x8 afh[2], afl[2], bfh[4], bfl[4];
    #pragma unroll
    for (int mt = 0; mt < 2; ++mt) {
      afh[mt] = *(const bf16x8*)&Ash[wave * 32 + mt * 16 + l16][quad * 8];
      if (Al) afl[mt] = *(const bf16x8*)&Asl[wave * 32 + mt * 16 + l16][quad * 8];
    }
    #pragma unroll
    for (int nt = 0; nt < 4; ++nt) {
      bfh[nt] = *(const bf16x8*)&Bsh[nt * 16 + l16][quad * 8];
      bfl[nt] = *(const bf16x8*)&Bsl[nt * 16 + l16][quad * 8];
    }
    #pragma unroll
    for (int mt = 0; mt < 2; ++mt)
      #pragma unroll
      for (int nt = 0; nt < 4; ++nt) {
        acc[mt][nt] = __builtin_amdgcn_mfma_f32_16x16x32_bf16(afh[mt], bfh[nt], acc[mt][nt], 0, 0, 0);
        acc[mt][nt] = __builtin_amdgcn_mfma_f32_16x16x32_bf16(afh[mt], bfl[nt], acc[mt][nt], 0, 0, 0);
        if (Al)
          acc[mt][nt] = __builtin_amdgcn_mfma_f32_16x16x32_bf16(afl[mt], bfh[nt], acc[mt][nt], 0, 0, 0);
      }
  }

  // epilogue: C row = quad*4+r (m), col = l16 (n)
  if (mode == 0) {
    if (wi == 2) {
      #pragma unroll
      for (int mt = 0; mt < 2; ++mt)
        #pragma unroll
        for (int nt = 0; nt < 4; ++nt) {
          const int col  = nbase + nt * 16 + l16;
          const int rowb = row0 + wave * 32 + mt * 16 + quad * 4;
          union { ushort4 v; short s[4]; } pk;
          #pragma unroll
          for (int r = 0; r < 4; ++r) pk.s[r] = (short)(bfbits(acc[mt][nt][r]) >> 16);
          *(ushort4*)&Vt[(size_t)col * MROWS + rowb] = pk.v;
        }
    } else {
      short* Op = wi == 0 ? Qp : wi == 1 ? Kp : Qip;
      #pragma unroll
      for (int mt = 0; mt < 2; ++mt)
        #pragma unroll
        for (int nt = 0; nt < 4; ++nt) {
          const int col  = nbase + nt * 16 + l16;
          const int h    = col / 40;
          const int pcol = h * 64 + (col - h * 40);
          const int rowb = row0 + wave * 32 + mt * 16 + quad * 4;
          #pragma unroll
          for (int r = 0; r < 4; ++r)
            Op[(size_t)(rowb + r) * QPAD + pcol] = (short)(bfbits(acc[mt][nt][r]) >> 16);
        }
    }
  } else {
    #pragma unroll
    for (int mt = 0; mt < 2; ++mt)
      #pragma unroll
      for (int nt = 0; nt < 4; ++nt) {
        const int col  = nbase + nt * 16 + l16;
        const int rowb = row0 + wave * 32 + mt * 16 + quad * 4;
        const float bb = bias[col];
        #pragma unroll
        for (int r = 0; r < 4; ++r)
          Of[(size_t)swizzle_row(rowb + r) * CDIM + col] = acc[mt][nt][r] + bb;
      }
  }
}

// ---------------------------------------------------------------------------
// Flash attention, bf16 MFMA, static-max softmax. 4 waves/block; wave owns
// 32 q-rows (2 tiles); KV step 64 keys staged in LDS (K from padded Kp,
// V^T pre-transposed). Tile->key map: QK^T tile kt loads K rows
// g=(l16&3)+4kt+16(l16>>2), so C keys = r+4kt+16quad -> lane holds 16
// CONSECUTIVE keys (quad*16+0..15) -> P stored as 2 aligned b128 writes.
// All LDS access patterns verified conflict-free (min 8-cycle b128).
// grid = (8 qblk, 8 heads, 16 = bf + 8*variant).
// ---------------------------------------------------------------------------
__global__ __launch_bounds__(256, 4) void attn_kernel(
    const short* __restrict__ Qp, const short* __restrict__ Qip,
    const short* __restrict__ Kp, const short* __restrict__ Vtg,
    short* __restrict__ AOh)
{
  const int qblk = blockIdx.x;   // 0..7 (128 q-rows per block)
  const int hh   = blockIdx.y;   // 0..7
  const int zz   = blockIdx.z;   // 0..15
  const int var  = zz >> 3;
  const int bf   = zz & 7;
  const int tid  = threadIdx.x;
  const int wave = tid >> 6;
  const int lane = tid & 63;
  const int quad = lane >> 4;
  const int l16  = lane & 15;

  const short* Q = var ? Qip : Qp;
  const int kvbase = var ? 0 : (bf << 10);
  const int coff = var * 320 + hh * 40;

  __shared__ short Ks[64][80];       // [key][kd 0..63] (40..63 zero via Kp pad)
  __shared__ short Vt[48][72];       // [dcol][key], rows 40..47 zero
  __shared__ short Ps[4][2][16][72]; // per-wave, per-qtile P buffer

  // zero Vt pad rows once (staging never writes them)
  if (tid < 64) {
    *(uint4*)&Vt[40 + (tid >> 3)][(tid & 7) * 8] = make_uint4(0, 0, 0, 0);
  }

  // Q B-fragments: 2 q-tiles of 16 rows; n = l16 = q-row, k = quad*8+j
  bf16x8 qf0[2], qf1[2];
  #pragma unroll
  for (int qt = 0; qt < 2; ++qt) {
    const short* qp = Q + (size_t)((bf << 10) + (qblk << 7) + (wave << 5) + (qt << 4) + l16) * QPAD + hh * 64;
    qf0[qt] = *(const bf16x8*)(qp + quad * 8);
    qf1[qt] = *(const bf16x8*)(qp + 32 + quad * 8);
  }

  f32x4 acc[2][3];
  float lsum[2] = {0.f, 0.f};
  #pragma unroll
  for (int qt = 0; qt < 2; ++qt)
    #pragma unroll
    for (int t = 0; t < 3; ++t) acc[qt][t] = (f32x4){0.f, 0.f, 0.f, 0.f};

  const short* Kb = Kp + (size_t)kvbase * QPAD + hh * 64;
  const short* Vb = Vtg + (size_t)(hh * 40) * MROWS + kvbase;

  const int gbase = (l16 & 3) + ((l16 >> 2) << 4);   // K-frag row base

  for (int s0 = 0; s0 < 1024; s0 += 64) {
    __syncthreads();
    // ---- stage: K 64 rows x 8 chunks (512) + V 40 rows x 8 chunks (320) ----
    #pragma unroll
    for (int pass = 0; pass < 4; ++pass) {
      int u = tid + (pass << 8);
      if (u < 512) {
        int key = u >> 3, c = u & 7;
        *(uint4*)&Ks[key][c * 8] =
            *(const uint4*)(Kb + (size_t)(s0 + key) * QPAD + c * 8);
      } else if (u < 832) {
        int v = u - 512;
        int dcol = v >> 3, ch = v & 7;
        *(uint4*)&Vt[dcol][ch * 8] =
            *(const uint4*)(Vb + (size_t)dcol * MROWS + s0 + ch * 8);
      }
    }
    __syncthreads();

    // ---- K A-fragments: tile kt, row m=l16 -> key g = gbase + 4*kt ----
    bf16x8 kb0[4], kb1[4];
    #pragma unroll
    for (int kt = 0; kt < 4; ++kt) {
      const short* kr = &Ks[gbase + 4 * kt][quad * 8];
      kb0[kt] = *(const bf16x8*)kr;
      kb1[kt] = *(const bf16x8*)(kr + 32);
    }

    #pragma unroll
    for (int qt = 0; qt < 2; ++qt) {
      // ---- S^T = K @ Q^T; C keys = 16*quad + 4*kt + r ----
      unsigned pbuf[8];
      float ls = 0.f;
      #pragma unroll
      for (int kt = 0; kt < 4; ++kt) {
        f32x4 st = (f32x4){0.f, 0.f, 0.f, 0.f};
        st = __builtin_amdgcn_mfma_f32_16x16x32_bf16(kb0[kt], qf0[qt], st, 0, 0, 0);
        st = __builtin_amdgcn_mfma_f32_16x16x32_bf16(kb1[kt], qf1[qt], st, 0, 0, 0);
        float p0 = __expf(st[0]);
        float p1 = __expf(st[1]);
        float p2 = __expf(st[2]);
        float p3 = __expf(st[3]);
        ls += (p0 + p1) + (p2 + p3);
        pbuf[kt * 2]     = pack2bf(p0, p1);
        pbuf[kt * 2 + 1] = pack2bf(p2, p3);
      }
      lsum[qt] += ls;

      // lane holds keys 16*quad + {0..15} for q-row l16 -> 2 b128 stores
      *(uint4*)&Ps[wave][qt][l16][quad * 16]     = *(uint4*)&pbuf[0];
      *(uint4*)&Ps[wave][qt][l16][quad * 16 + 8] = *(uint4*)&pbuf[4];

      // wave-internal LDS RAW (cross-lane): drain before reading P
      asm volatile("s_waitcnt lgkmcnt(0)" ::: "memory");

      // ---- P @ V ----
      bf16x8 pa0 = *(const bf16x8*)&Ps[wave][qt][l16][quad * 8];
      bf16x8 pa1 = *(const bf16x8*)&Ps[wave][qt][l16][32 + quad * 8];
      #pragma unroll
      for (int t = 0; t < 3; ++t) {
        bf16x8 v0 = *(const bf16x8*)&Vt[t * 16 + l16][quad * 8];
        bf16x8 v1 = *(const bf16x8*)&Vt[t * 16 + l16][32 + quad * 8];
        acc[qt][t] = __builtin_amdgcn_mfma_f32_16x16x32_bf16(pa0, v0, acc[qt][t], 0, 0, 0);
        acc[qt][t] = __builtin_amdgcn_mfma_f32_16x16x32_bf16(pa1, v1, acc[qt][t], 0, 0, 0);
      }
    }
  }

  // ---- epilogue: normalize by deferred denominator, write bf16 ----
  #pragma unroll
  for (int qt = 0; qt < 2; ++qt) {
    float li = lsum[qt];
    li += __shfl_xor(li, 16);
    li += __shfl_xor(li, 32);
    float inv = 1.f / li;                       // denom for q-row l16
    float invr[4];
    #pragma unroll
    for (int r = 0; r < 4; ++r) invr[r] = __shfl(inv, quad * 4 + r, 64);

    const int baserow = (bf << 10) + (qblk << 7) + (wave << 5) + (qt << 4) + quad * 4;
    #pragma unroll
    for (int t = 0; t < 3; ++t) {
      int dcol = t * 16 + l16;
      if (dcol < 40) {
        short* op = AOh + (size_t)baserow * 640 + coff + dcol;
        #pragma unroll
        for (int r = 0; r < 4; ++r)
          op[(size_t)r * 640] = (short)(bfbits(acc[qt][t][r] * invr[r]) >> 16);
      }
    }
  }
}

// ---------------------------------------------------------------------------
extern "C" void kernel_launch(void* const* d_in, const int* in_sizes, int n_in,
                              void* d_out, int out_size, void* d_ws, size_t ws_size,
                              hipStream_t stream) {
  const float* hidden  = (const float*)d_in[0];
  const float* Wq      = (const float*)d_in[1];
  const float* Wk      = (const float*)d_in[2];
  const float* Wv      = (const float*)d_in[3];
  const float* Wo      = (const float*)d_in[4];
  const float* bo      = (const float*)d_in[5];
  const float* Wq_i2v  = (const float*)d_in[6];
  const float* Wo_i2v  = (const float*)d_in[7];
  const float* bo_i2v  = (const float*)d_in[8];
  float* out = (float*)d_out;

  const size_t SZ  = (size_t)MROWS * CDIM;    // 2,621,440
  const size_t SZP = (size_t)MROWS * QPAD;    // 4,194,304
  short* Ah  = (short*)d_ws;                  // [8192][320] split hidden (hi)
  short* Al  = Ah + SZ;                       // [8192][320] (lo)
  short* AOh = Ah;                            // attn out [8192][640] — aliases Ah/Al (dead after G1)
  short* Qp  = Al + SZ;                       // [8192][512] padded
  short* Kp  = Qp + SZP;                      // [8192][512] padded
  short* Qip = Kp + SZP;                      // [8192][512] padded
  short* Vt  = Qip + SZP;                     // [328][8192] (rows 320..327 slack)
  short* WTh = Vt + (size_t)328 * MROWS;
  short* WTl = WTh + 409600;
  short* WFh = WTl + 409600;                  // [320][640] transposed [Wo; Wc]
  short* WFl = WFh + 204800;
  float* Wc  = (float*)(WFl + 204800);
  float* bc  = Wc + 102400;

  const float qscale = 0.15811388300841898f;  // 1/sqrt(40), folded into Q/Q_i2v

  // P1: Wc = Wo_i2v @ Wo
  wc_kernel<<<dim3(5, 5), 256, 0, stream>>>(Wo_i2v, Wo, Wc);

  // P2: split/transpose/zero-pad
  pack_kernel<<<dim3(264), 256, 0, stream>>>(
      hidden, Wq, Wk, Wv, Wq_i2v, Wo, Wc, bo, bo_i2v,
      Ah, Al, WTh, WTl, WFh, WFl, bc, Qp, Kp, Qip, qscale);

  // G1: projections (3-term split MFMA) -> padded Q/K/Qi + V^T
  mfma_gemm<<<dim3(64, 20), 256, 0, stream>>>(
      Ah, Al, WTh, WTl, 320, 0, Qp, Kp, Vt, Qip, nullptr, nullptr);

  // A: both attentions (base: per-frame KV; i2v: frame-0 KV) -> AOh [8192][640]
  attn_kernel<<<dim3(8, 8, 16), 256, 0, stream>>>(Qp, Qip, Kp, Vt, AOh);

  // G2: out = [base|i2v] @ [Wo; Wo_i2v@Wo] + (bo + bo_i2v@Wo), scattered (2-term)
  mfma_gemm<<<dim3(64, 5), 256, 0, stream>>>(
      AOh, nullptr, WFh, WFl, 640, 1, nullptr, nullptr, nullptr, nullptr, out, bc);
}